// Round 1
// baseline (4480.108 us; speedup 1.0000x reference)
//
#include <hip/hip_runtime.h>
#include <cstddef>

namespace {

constexpr int B  = 4;
constexpr int L  = 2048;
constexpr int D  = 1024;
constexpr int H  = 16;
constexpr int DK = 64;              // == DV
constexpr int HD = H * DK;          // 1024
constexpr float INV_TEMP = 0.125f;  // 1/8
constexpr size_t NH = (size_t)B * H * L * DK;  // 8,388,608 floats per head-tensor
constexpr int LDP = 68;             // padded LDS row (floats); 68*4 B = 272 B, 16B-aligned rows

// ---------------------------------------------------------------------------
// Projection GEMM: outh[b,h,l,d] = (X[m,:] @ W[:,n] + bias[n]) * scale
//   X: [8192,1024] row-major, W: [1024,1024], outh: [B,H,L,64] head-major
// BM=BN=BK=64, 256 threads, 4x4 micro-tile.
// ---------------------------------------------------------------------------
__global__ __launch_bounds__(256)
void gemm_proj(const float* __restrict__ X, const float* __restrict__ W,
               const float* __restrict__ bias, float* __restrict__ outh,
               float scale)
{
    __shared__ float Ast[64][LDP];  // [k][m]  (A transposed in LDS)
    __shared__ float Bs[64][LDP];   // [k][n]
    const int tid = threadIdx.x;
    const int tx = tid & 15, ty = tid >> 4;
    const int m0 = blockIdx.x << 6;
    const int n0 = blockIdx.y << 6;
    float c[4][4] = {};

    for (int k0 = 0; k0 < D; k0 += 64) {
#pragma unroll
        for (int it = 0; it < 4; ++it) {
            const int idx = (it << 10) + (tid << 2);   // 0..4095, 16B chunks
            const int r = idx >> 6, cb = idx & 63;
            // A tile: rows m0..m0+63, cols k0..k0+63 (row-major, contiguous 256B rows)
            const float4 a4 = *(const float4*)(X + (size_t)(m0 + r) * D + k0 + cb);
            Ast[cb + 0][r] = a4.x; Ast[cb + 1][r] = a4.y;
            Ast[cb + 2][r] = a4.z; Ast[cb + 3][r] = a4.w;
            // B tile: rows k0..k0+63, cols n0..n0+63
            *(float4*)&Bs[r][cb] = *(const float4*)(W + (size_t)(k0 + r) * HD + n0 + cb);
        }
        __syncthreads();
#pragma unroll
        for (int kk = 0; kk < 64; ++kk) {
            const float4 a4 = *(const float4*)&Ast[kk][ty << 2];
            const float4 b4 = *(const float4*)&Bs[kk][tx << 2];
            const float a[4]  = {a4.x, a4.y, a4.z, a4.w};
            const float bb[4] = {b4.x, b4.y, b4.z, b4.w};
#pragma unroll
            for (int i = 0; i < 4; ++i)
#pragma unroll
                for (int j = 0; j < 4; ++j)
                    c[i][j] = fmaf(a[i], bb[j], c[i][j]);
        }
        __syncthreads();
    }

    const int h  = n0 >> 6;      // n0 is a multiple of 64 -> single head per tile
    const int dd = tx << 2;
    const float4 b4 = *(const float4*)(bias + n0 + dd);
#pragma unroll
    for (int i = 0; i < 4; ++i) {
        const int m = m0 + (ty << 2) + i;
        const int b = m >> 11;           // / 2048
        const int l = m & (L - 1);
        float4 r;
        r.x = (c[i][0] + b4.x) * scale;
        r.y = (c[i][1] + b4.y) * scale;
        r.z = (c[i][2] + b4.z) * scale;
        r.w = (c[i][3] + b4.w) * scale;
        *(float4*)(outh + ((((size_t)b * H + h) * L + l) << 6) + dd) = r;
    }
}

// ---------------------------------------------------------------------------
// Scores: att[bh,q,j] = sum_d Qh[bh,q,d] * Kh[bh,j,d]   (Q pre-scaled by 1/TEMP)
// masked positions (mask==0) -> -1e9.  One 64x64 tile per block, K=64 one-shot.
// ---------------------------------------------------------------------------
__global__ __launch_bounds__(256)
void scores_kernel(const float* __restrict__ Qh, const float* __restrict__ Kh,
                   const int* __restrict__ mask, float* __restrict__ att)
{
    __shared__ float Qt[64][LDP];  // [d][q]
    __shared__ float Kt[64][LDP];  // [d][j]
    const int tid = threadIdx.x;
    const int tx = tid & 15, ty = tid >> 4;
    const int j0 = blockIdx.x << 6;
    const int q0 = blockIdx.y << 6;
    const int bh = blockIdx.z;
    const int b  = bh >> 4;     // / H
    const float* Qbh = Qh + (size_t)bh * L * DK;
    const float* Kbh = Kh + (size_t)bh * L * DK;

#pragma unroll
    for (int it = 0; it < 4; ++it) {
        const int idx = (it << 10) + (tid << 2);
        const int r = idx >> 6, cb = idx & 63;
        const float4 a4 = *(const float4*)(Qbh + (size_t)(q0 + r) * DK + cb);
        Qt[cb + 0][r] = a4.x; Qt[cb + 1][r] = a4.y;
        Qt[cb + 2][r] = a4.z; Qt[cb + 3][r] = a4.w;
        const float4 k4 = *(const float4*)(Kbh + (size_t)(j0 + r) * DK + cb);
        Kt[cb + 0][r] = k4.x; Kt[cb + 1][r] = k4.y;
        Kt[cb + 2][r] = k4.z; Kt[cb + 3][r] = k4.w;
    }
    __syncthreads();

    float c[4][4] = {};
#pragma unroll
    for (int kk = 0; kk < 64; ++kk) {
        const float4 a4 = *(const float4*)&Qt[kk][ty << 2];
        const float4 b4 = *(const float4*)&Kt[kk][tx << 2];
        const float a[4]  = {a4.x, a4.y, a4.z, a4.w};
        const float bb[4] = {b4.x, b4.y, b4.z, b4.w};
#pragma unroll
        for (int i = 0; i < 4; ++i)
#pragma unroll
            for (int j = 0; j < 4; ++j)
                c[i][j] = fmaf(a[i], bb[j], c[i][j]);
    }

    const int jc = j0 + (tx << 2);
#pragma unroll
    for (int i = 0; i < 4; ++i) {
        const int q = q0 + (ty << 2) + i;
        const int4 mm = *(const int4*)(mask + ((size_t)b * L + q) * L + jc);
        float4 r;
        r.x = mm.x ? c[i][0] : -1e9f;
        r.y = mm.y ? c[i][1] : -1e9f;
        r.z = mm.z ? c[i][2] : -1e9f;
        r.w = mm.w ? c[i][3] : -1e9f;
        *(float4*)(att + ((size_t)bh * L + q) * L + jc) = r;
    }
}

// ---------------------------------------------------------------------------
// In-place masked-row softmax over the last dim (2048). One block per row.
// ---------------------------------------------------------------------------
__global__ __launch_bounds__(256)
void softmax_kernel(float* __restrict__ att)
{
    __shared__ float red[256];
    float* p = att + (size_t)blockIdx.x * L;
    const int tid = threadIdx.x;
    float4 v0 = *(const float4*)(p + (tid << 3));
    float4 v1 = *(const float4*)(p + (tid << 3) + 4);

    float mx = fmaxf(fmaxf(fmaxf(v0.x, v0.y), fmaxf(v0.z, v0.w)),
                     fmaxf(fmaxf(v1.x, v1.y), fmaxf(v1.z, v1.w)));
    red[tid] = mx;
    __syncthreads();
    for (int s = 128; s > 0; s >>= 1) {
        if (tid < s) red[tid] = fmaxf(red[tid], red[tid + s]);
        __syncthreads();
    }
    const float rowmax = red[0];
    __syncthreads();

    v0.x = __expf(v0.x - rowmax); v0.y = __expf(v0.y - rowmax);
    v0.z = __expf(v0.z - rowmax); v0.w = __expf(v0.w - rowmax);
    v1.x = __expf(v1.x - rowmax); v1.y = __expf(v1.y - rowmax);
    v1.z = __expf(v1.z - rowmax); v1.w = __expf(v1.w - rowmax);
    red[tid] = (v0.x + v0.y + v0.z + v0.w) + (v1.x + v1.y + v1.z + v1.w);
    __syncthreads();
    for (int s = 128; s > 0; s >>= 1) {
        if (tid < s) red[tid] += red[tid + s];
        __syncthreads();
    }
    const float inv = 1.0f / red[0];

    v0.x *= inv; v0.y *= inv; v0.z *= inv; v0.w *= inv;
    v1.x *= inv; v1.y *= inv; v1.z *= inv; v1.w *= inv;
    *(float4*)(p + (tid << 3))     = v0;
    *(float4*)(p + (tid << 3) + 4) = v1;
}

// ---------------------------------------------------------------------------
// att @ V: O[bh,q,d] = sum_k att[bh,q,k] * Vh[bh,k,d].  BM=64, BN=64(=DV), BK=64.
// ---------------------------------------------------------------------------
__global__ __launch_bounds__(256)
void attv_kernel(const float* __restrict__ att, const float* __restrict__ Vh,
                 float* __restrict__ O)
{
    __shared__ float Ast[64][LDP];
    __shared__ float Bs[64][LDP];
    const int tid = threadIdx.x;
    const int tx = tid & 15, ty = tid >> 4;
    const int m0 = blockIdx.x << 6;
    const int bh = blockIdx.y;
    const float* Abh = att + (size_t)bh * L * L;
    const float* Vbh = Vh + (size_t)bh * L * DK;
    float c[4][4] = {};

    for (int k0 = 0; k0 < L; k0 += 64) {
#pragma unroll
        for (int it = 0; it < 4; ++it) {
            const int idx = (it << 10) + (tid << 2);
            const int r = idx >> 6, cb = idx & 63;
            const float4 a4 = *(const float4*)(Abh + (size_t)(m0 + r) * L + k0 + cb);
            Ast[cb + 0][r] = a4.x; Ast[cb + 1][r] = a4.y;
            Ast[cb + 2][r] = a4.z; Ast[cb + 3][r] = a4.w;
            *(float4*)&Bs[r][cb] = *(const float4*)(Vbh + (size_t)(k0 + r) * DK + cb);
        }
        __syncthreads();
#pragma unroll
        for (int kk = 0; kk < 64; ++kk) {
            const float4 a4 = *(const float4*)&Ast[kk][ty << 2];
            const float4 b4 = *(const float4*)&Bs[kk][tx << 2];
            const float a[4]  = {a4.x, a4.y, a4.z, a4.w};
            const float bb[4] = {b4.x, b4.y, b4.z, b4.w};
#pragma unroll
            for (int i = 0; i < 4; ++i)
#pragma unroll
                for (int j = 0; j < 4; ++j)
                    c[i][j] = fmaf(a[i], bb[j], c[i][j]);
        }
        __syncthreads();
    }

    const int dd = tx << 2;
#pragma unroll
    for (int i = 0; i < 4; ++i) {
        const int m = m0 + (ty << 2) + i;
        float4 r;
        r.x = c[i][0]; r.y = c[i][1]; r.z = c[i][2]; r.w = c[i][3];
        *(float4*)(O + (((size_t)bh * L + m) << 6) + dd) = r;
    }
}

// ---------------------------------------------------------------------------
// FC: out[m,n] = sum_k Oflat[m,k]*Wfc[k,n] + bfc[n] + resid[m,n]
//   Oflat[m,k]: m=b*L+l, k=h*64+d -> O[((b*H+h)*L+l)*64+d]
// ---------------------------------------------------------------------------
__global__ __launch_bounds__(256)
void fc_kernel(const float* __restrict__ O, const float* __restrict__ Wfc,
               const float* __restrict__ bfc, const float* __restrict__ resid,
               float* __restrict__ out)
{
    __shared__ float Ast[64][LDP];
    __shared__ float Bs[64][LDP];
    const int tid = threadIdx.x;
    const int tx = tid & 15, ty = tid >> 4;
    const int m0 = blockIdx.x << 6;
    const int n0 = blockIdx.y << 6;
    float c[4][4] = {};

    for (int k0 = 0; k0 < HD; k0 += 64) {
        const int h = k0 >> 6;   // k-tile lies inside one head
#pragma unroll
        for (int it = 0; it < 4; ++it) {
            const int idx = (it << 10) + (tid << 2);
            const int r = idx >> 6, cb = idx & 63;
            const int m = m0 + r;
            const int b = m >> 11, l = m & (L - 1);
            const float4 a4 = *(const float4*)(O + ((((size_t)b * H + h) * L + l) << 6) + cb);
            Ast[cb + 0][r] = a4.x; Ast[cb + 1][r] = a4.y;
            Ast[cb + 2][r] = a4.z; Ast[cb + 3][r] = a4.w;
            *(float4*)&Bs[r][cb] = *(const float4*)(Wfc + (size_t)(k0 + r) * D + n0 + cb);
        }
        __syncthreads();
#pragma unroll
        for (int kk = 0; kk < 64; ++kk) {
            const float4 a4 = *(const float4*)&Ast[kk][ty << 2];
            const float4 b4 = *(const float4*)&Bs[kk][tx << 2];
            const float a[4]  = {a4.x, a4.y, a4.z, a4.w};
            const float bb[4] = {b4.x, b4.y, b4.z, b4.w};
#pragma unroll
            for (int i = 0; i < 4; ++i)
#pragma unroll
                for (int j = 0; j < 4; ++j)
                    c[i][j] = fmaf(a[i], bb[j], c[i][j]);
        }
        __syncthreads();
    }

    const int nn = n0 + (tx << 2);
    const float4 bb4 = *(const float4*)(bfc + nn);
#pragma unroll
    for (int i = 0; i < 4; ++i) {
        const int m = m0 + (ty << 2) + i;
        const float4 q4 = *(const float4*)(resid + (size_t)m * D + nn);
        float4 r;
        r.x = c[i][0] + bb4.x + q4.x;
        r.y = c[i][1] + bb4.y + q4.y;
        r.z = c[i][2] + bb4.z + q4.z;
        r.w = c[i][3] + bb4.w + q4.w;
        *(float4*)(out + (size_t)m * D + nn) = r;
    }
}

}  // namespace

extern "C" void kernel_launch(void* const* d_in, const int* in_sizes, int n_in,
                              void* d_out, int out_size, void* d_ws, size_t ws_size,
                              hipStream_t stream)
{
    const float* q    = (const float*)d_in[0];
    const float* k    = (const float*)d_in[1];
    const float* v    = (const float*)d_in[2];
    const int*   mask = (const int*)d_in[3];
    const float* Wq   = (const float*)d_in[4];
    const float* bq   = (const float*)d_in[5];
    const float* Wk   = (const float*)d_in[6];
    const float* bk   = (const float*)d_in[7];
    const float* Wv   = (const float*)d_in[8];
    const float* bv   = (const float*)d_in[9];
    const float* Wfc  = (const float*)d_in[10];
    const float* bfc  = (const float*)d_in[11];

    float* out = (float*)d_out;                       // [B,L,D]
    float* att = out + (size_t)B * L * D;             // [B,H,L,L]

    float* Qh = (float*)d_ws;       // [B,H,L,64]
    float* Kh = Qh + NH;
    float* Vh = Kh + NH;
    float* O  = Qh;                 // alias: Qh dead after scores_kernel

    const dim3 blk(256);

    gemm_proj<<<dim3(128, 16), blk, 0, stream>>>(q, Wq, bq, Qh, INV_TEMP);
    gemm_proj<<<dim3(128, 16), blk, 0, stream>>>(k, Wk, bk, Kh, 1.0f);
    gemm_proj<<<dim3(128, 16), blk, 0, stream>>>(v, Wv, bv, Vh, 1.0f);

    scores_kernel<<<dim3(32, 32, B * H), blk, 0, stream>>>(Qh, Kh, mask, att);
    softmax_kernel<<<dim3(B * H * L), blk, 0, stream>>>(att);
    attv_kernel<<<dim3(32, B * H), blk, 0, stream>>>(att, Vh, O);
    fc_kernel<<<dim3(128, 16), blk, 0, stream>>>(O, Wfc, bfc, q, out);
}